// Round 7
// baseline (170.483 us; speedup 1.0000x reference)
//
#include <hip/hip_runtime.h>

// Head attention forward, MI355X gfx950.
// B=8, T=2048, C=1024, H=64. Scale C^-0.5*log2e folded into q at gemm epilogue.
// R7 structure:
//   zero_out:  zero d_out (o-numerator accumulator) + Lws (row denominators)
//   wpack:     Wk|Wq|Wv fp32 -> bf16 Wct[192][1024], LDS-transposed (coalesced)
//   qkv_gemm:  32x192 tile, BK=128, 8 waves (m=w&1, ng=w>>1), A double-buffered
//              in LDS (stage step k+1 while computing k), B direct from L2.
//   flash:     chunked split-s flash attn: grid (j, b, chunk); block = 2 waves
//              (q-tiles 2j, 2j+1), <=8 steps of 64 keys per block; K/V staged
//              via global_load_lds, double-buffered, XOR-swizzled. No-max
//              softmax (scores O(+-2)); linear combine via atomicAdd into out.
//   normalize: out[row][:] /= Lws[row].
//
// ws layout:
//   u16:  [0, BTH) k | [BTH, 2BTH) q' | [2BTH, 3BTH) vt [b][h][t]
//         [3BTH, +192K) Wct [n][k]
//   f32:  Lws[16384] at byte offset (3*BTH + 192*1024)*2

#define B_ 8
#define T_ 2048
#define C_ 1024
#define H_ 64
#define BTH (B_ * T_ * H_)
#define LWS_OFF ((size_t)3 * BTH + 192 * 1024)  // in u16 units

typedef unsigned short u16;
typedef float f32x4 __attribute__((ext_vector_type(4)));
typedef __bf16 bf16x8 __attribute__((ext_vector_type(8)));
#define AS1 __attribute__((address_space(1)))
#define AS3 __attribute__((address_space(3)))

__device__ __forceinline__ u16 f2bf(float f) {
  union { float f; unsigned u; } c; c.f = f;
  unsigned u = c.u;
  return (u16)((u + 0x7FFFu + ((u >> 16) & 1u)) >> 16);  // RNE
}

__device__ __forceinline__ bf16x8 cvt8(const float4 a, const float4 b) {
  bf16x8 r;
  r[0] = (__bf16)a.x; r[1] = (__bf16)a.y; r[2] = (__bf16)a.z; r[3] = (__bf16)a.w;
  r[4] = (__bf16)b.x; r[5] = (__bf16)b.y; r[6] = (__bf16)b.z; r[7] = (__bf16)b.w;
  return r;
}

// ---------------------------------------------------------------------------
// zero_out: out (1048576 f32) + Lws (16384 f32) = 266240 float4... /4 = 266240
// grid 1040, block 256: i < 262144 -> out4, else Lws4.
// ---------------------------------------------------------------------------
__global__ __launch_bounds__(256)
void zero_out(float4* __restrict__ out4, float4* __restrict__ l4) {
  const int i = blockIdx.x * 256 + threadIdx.x;
  const float4 z = make_float4(0.f, 0.f, 0.f, 0.f);
  if (i < 262144) out4[i] = z;
  else            l4[i - 262144] = z;
}

// ---------------------------------------------------------------------------
// wpack: Wct[g*64+h][k] = W_g[k][h], bf16, via LDS transpose (both sides
// coalesced). grid (3,16), block 256.
// ---------------------------------------------------------------------------
__global__ __launch_bounds__(256)
void wpack(const float* __restrict__ Wk, const float* __restrict__ Wq,
           const float* __restrict__ Wv, u16* __restrict__ Wct) {
  __shared__ float t[64][65];
  const int g  = blockIdx.x;
  const int k0 = blockIdx.y * 64;
  const float* __restrict__ W = (g == 0) ? Wk : (g == 1) ? Wq : Wv;
  const int c = threadIdx.x & 63, r4 = threadIdx.x >> 6;
#pragma unroll
  for (int it = 0; it < 16; ++it) {
    const int row = it * 4 + r4;                 // kk-local
    t[row][c] = W[(size_t)(k0 + row) * H_ + c];  // coalesced read
  }
  __syncthreads();
#pragma unroll
  for (int it = 0; it < 16; ++it) {
    const int hrow = it * 4 + r4;
    Wct[(size_t)(g * 64 + hrow) * C_ + k0 + c] = f2bf(t[c][hrow]);  // coalesced
  }
}

// ---------------------------------------------------------------------------
// qkv_gemm: grid (512), block 512 (8 waves). Tile 32 rows x 192 cols, BK=128.
// Wave w: m-tile = w&1, n-group = w>>1 (48 cols, 3 n-tiles).
// LDS A: double-buffered bf16 [32][16 chunks of 8], chunk' = c ^ (row&15).
//   stage: thread t: srow=t>>4, sch=t&15, 8 floats -> 1 ds_write_b128.
//   read:  frag f: row=m*16+l15, chunk (4f+quad)^l15 -> 2-way banks (free).
// Pipeline: ds_write(k+1 from regs loaded at k-1) | compute(k) | load x(k+2),
// B(k) loaded right after barrier, consumed ~150cy later. 1 barrier/step.
// ---------------------------------------------------------------------------
__global__ __launch_bounds__(512)
void qkv_gemm(const float* __restrict__ x, const u16* __restrict__ Wct,
              u16* __restrict__ ws) {
  __shared__ u16 As[2][32 * 128];  // 2 x 8 KB
  const int tid  = threadIdx.x;
  const int wave = tid >> 6, lane = tid & 63;
  const int l15 = lane & 15, quad = lane >> 4;
  const int m = wave & 1, ng = wave >> 1;
  const int r0 = blockIdx.x * 32;
  // staging
  const int srow = tid >> 4, sch = tid & 15;
  const float* __restrict__ xsrc = x + (size_t)(r0 + srow) * C_ + sch * 8;
  const int wslot = srow * 128 + (sch ^ (srow & 15)) * 8;
  // compute
  const u16* __restrict__ wp = Wct + (size_t)(ng * 48 + l15) * C_ + quad * 8;
  const int arow = (m * 16 + l15) * 128;
  const f32x4 z = {0.f, 0.f, 0.f, 0.f};
  f32x4 acc[3];
#pragma unroll
  for (int ni = 0; ni < 3; ++ni) acc[ni] = z;

  // prologue: stage k=0, preload x(1)
  float4 xa0 = *(const float4*)(xsrc);
  float4 xa1 = *(const float4*)(xsrc + 4);
  *(bf16x8*)(&As[0][wslot]) = cvt8(xa0, xa1);
  xa0 = *(const float4*)(xsrc + 128);
  xa1 = *(const float4*)(xsrc + 132);
  __syncthreads();

#pragma unroll
  for (int ks = 0; ks < 8; ++ks) {
    const int cur = ks & 1;
    const int k0 = ks * 128;
    // B(ks) loads: issue first, consumed after ds_reads
    bf16x8 Bf[3][4];
#pragma unroll
    for (int ni = 0; ni < 3; ++ni)
#pragma unroll
      for (int f = 0; f < 4; ++f)
        Bf[ni][f] = *(const bf16x8*)(wp + (size_t)ni * 16 * C_ + k0 + f * 32);
    // stage A(ks+1) into other buffer (xa loaded one step ago)
    if (ks < 7) *(bf16x8*)(&As[cur ^ 1][wslot]) = cvt8(xa0, xa1);
    if (ks < 6) {  // prefetch x(ks+2)
      xa0 = *(const float4*)(xsrc + (ks + 2) * 128);
      xa1 = *(const float4*)(xsrc + (ks + 2) * 128 + 4);
    }
#pragma unroll
    for (int f = 0; f < 4; ++f) {
      const bf16x8 a = *(const bf16x8*)(&As[cur][arow + (((4 * f + quad) ^ l15) * 8)]);
#pragma unroll
      for (int ni = 0; ni < 3; ++ni)
        acc[ni] = __builtin_amdgcn_mfma_f32_16x16x32_bf16(a, Bf[ni][f], acc[ni], 0, 0, 0);
    }
    __syncthreads();
  }
  // epilogue: col = ng*48 + ni*16 + l15 (g = col>>6 wave-uniform per ni)
  const float SCLL = 0.03125f * 1.44269504088896f;  // C^-0.5 * log2(e) -> q
  const int rowg = r0 + m * 16;
  const int bb = r0 >> 11;
  const int tb = (rowg & 2047) + quad * 4;
#pragma unroll
  for (int ni = 0; ni < 3; ++ni) {
    const int col = ng * 48 + ni * 16 + l15;
    const int g = col >> 6, h = col & 63;
    f32x4 a = acc[ni];
    if (g == 1) { a[0] *= SCLL; a[1] *= SCLL; a[2] *= SCLL; a[3] *= SCLL; }
    if (g < 2) {
      u16* op = ws + (size_t)g * BTH + (size_t)(rowg + quad * 4) * H_ + h;
#pragma unroll
      for (int r = 0; r < 4; ++r) op[(size_t)r * H_] = f2bf(a[r]);
    } else {
      uint2 pk;
      pk.x = (unsigned)f2bf(a[0]) | ((unsigned)f2bf(a[1]) << 16);
      pk.y = (unsigned)f2bf(a[2]) | ((unsigned)f2bf(a[3]) << 16);
      *(uint2*)(ws + (size_t)2 * BTH + (size_t)(bb * H_ + h) * T_ + tb) = pk;
    }
  }
}

// ---------------------------------------------------------------------------
// flash: grid (64, 8, 4), block 128 (2 waves). Block (j, b, c): wave wv owns
// q-tile qt=2j+wv; handles s-steps [8c, min(8c+8, ns)), ns=(2j+5)>>2 (equal
// for both waves). Blocks with c >= ceil(ns/8) exit. K/V double-buffered
// swizzled LDS via global_load_lds. No-max softmax; un-normalized o
// atomicAdd'ed into out, row-sum l into Lws; normalize kernel divides.
// ---------------------------------------------------------------------------
__global__ __launch_bounds__(128)
void flash(const u16* __restrict__ ws, float* __restrict__ out, float* __restrict__ Lws) {
  const int j  = blockIdx.x;
  const int ns = (2 * j + 5) >> 2;
  const int c  = blockIdx.z;
  if (c * 8 >= ns) return;  // uniform exit (j-dependent only)
  const int st0   = c * 8;
  const int stEnd = min(st0 + 8, ns);
  __shared__ u16 Ks[2][64 * 64];
  __shared__ u16 Vs[2][64 * 64];
  __shared__ __bf16 Pt[2][16 * 72];
  const u16* __restrict__ kg = ws;
  const u16* __restrict__ qg = ws + BTH;
  const u16* __restrict__ vt = ws + (size_t)2 * BTH;
  const int b    = blockIdx.y;
  const int tid  = threadIdx.x;
  const int wv   = tid >> 6;
  const int lane = tid & 63;
  const int l15  = lane & 15, quad = lane >> 4;
  const int qt   = 2 * j + wv;
  const int t0   = qt * 16;
  const u16* kb0 = kg + (size_t)b * T_ * H_;
  const u16* vb0 = vt + (size_t)b * H_ * T_;
  const int srow = tid >> 3, scp = tid & 7;  // slot = jj*128+tid -> row jj*16+srow
  const u16* qrow = qg + ((size_t)(b * T_ + t0 + l15)) * H_ + quad * 8;
  const bf16x8 qf0 = *(const bf16x8*)qrow;
  const bf16x8 qf1 = *(const bf16x8*)(qrow + 32);
  __bf16* pt = &Pt[wv][0];
  const f32x4 z = {0.f, 0.f, 0.f, 0.f};
  f32x4 o[4];
  float lr[4] = {0.f, 0.f, 0.f, 0.f};
#pragma unroll
  for (int hi = 0; hi < 4; ++hi) o[hi] = z;

  // prologue: stage step st0 into buf 0
  {
    const int s0 = st0 * 64;
#pragma unroll
    for (int jj = 0; jj < 4; ++jj) {
      const int row = jj * 16 + srow;
      const int sc  = scp ^ (row & 7);
      __builtin_amdgcn_global_load_lds(
          (const AS1 unsigned*)(kb0 + (size_t)(s0 + row) * H_ + sc * 8),
          (AS3 unsigned*)(&Ks[0][(jj * 128 + tid) * 8]), 16, 0, 0);
      __builtin_amdgcn_global_load_lds(
          (const AS1 unsigned*)(vb0 + (size_t)row * T_ + s0 + sc * 8),
          (AS3 unsigned*)(&Vs[0][(jj * 128 + tid) * 8]), 16, 0, 0);
    }
  }
  __syncthreads();

#pragma unroll 1
  for (int st = st0; st < stEnd; ++st) {
    const int cur = (st - st0) & 1;
    if (st + 1 < stEnd) {  // stage next into other buffer
      const int s1 = (st + 1) * 64;
#pragma unroll
      for (int jj = 0; jj < 4; ++jj) {
        const int row = jj * 16 + srow;
        const int sc  = scp ^ (row & 7);
        __builtin_amdgcn_global_load_lds(
            (const AS1 unsigned*)(kb0 + (size_t)(s1 + row) * H_ + sc * 8),
            (AS3 unsigned*)(&Ks[cur ^ 1][(jj * 128 + tid) * 8]), 16, 0, 0);
        __builtin_amdgcn_global_load_lds(
            (const AS1 unsigned*)(vb0 + (size_t)row * T_ + s1 + sc * 8),
            (AS3 unsigned*)(&Vs[cur ^ 1][(jj * 128 + tid) * 8]), 16, 0, 0);
      }
    }
    const u16* Kc = &Ks[cur][0];
    const u16* Vc = &Vs[cur][0];
    const int sw = (l15 & 7);
    f32x4 s[4];
#pragma unroll
    for (int ni = 0; ni < 4; ++ni) {
      const u16* kr = Kc + (ni * 16 + l15) * 64;
      const bf16x8 k0 = *(const bf16x8*)(kr + ((quad       ^ sw) * 8));
      const bf16x8 k1 = *(const bf16x8*)(kr + (((4 + quad) ^ sw) * 8));
      s[ni] = __builtin_amdgcn_mfma_f32_16x16x32_bf16(qf0, k0, z, 0, 0, 0);
      s[ni] = __builtin_amdgcn_mfma_f32_16x16x32_bf16(qf1, k1, s[ni], 0, 0, 0);
    }
    if (st == ns - 1) {  // causal mask (global last step only)
      const int s0 = st * 64;
#pragma unroll
      for (int ni = 0; ni < 4; ++ni)
#pragma unroll
        for (int r = 0; r < 4; ++r)
          if (s0 + ni * 16 + l15 > t0 + quad * 4 + r) s[ni][r] = -1e30f;
    }
    float p[4][4];
#pragma unroll
    for (int ni = 0; ni < 4; ++ni)
#pragma unroll
      for (int r = 0; r < 4; ++r) p[ni][r] = __builtin_amdgcn_exp2f(s[ni][r]);
#pragma unroll
    for (int r = 0; r < 4; ++r)
      lr[r] += (p[0][r] + p[1][r]) + (p[2][r] + p[3][r]);
#pragma unroll
    for (int ni = 0; ni < 4; ++ni)
#pragma unroll
      for (int r = 0; r < 4; ++r)
        pt[(quad * 4 + r) * 72 + ni * 16 + l15] = (__bf16)p[ni][r];
    asm volatile("s_waitcnt lgkmcnt(0)" ::: "memory");
    const bf16x8 pa0 = *(const bf16x8*)(pt + l15 * 72 + quad * 8);
    const bf16x8 pa1 = *(const bf16x8*)(pt + l15 * 72 + 32 + quad * 8);
    asm volatile("" ::: "memory");
#pragma unroll
    for (int hi = 0; hi < 4; ++hi) {
      const u16* vr = Vc + (hi * 16 + l15) * 64;
      const bf16x8 v0 = *(const bf16x8*)(vr + ((quad       ^ sw) * 8));
      const bf16x8 v1 = *(const bf16x8*)(vr + (((4 + quad) ^ sw) * 8));
      o[hi] = __builtin_amdgcn_mfma_f32_16x16x32_bf16(pa0, v0, o[hi], 0, 0, 0);
      o[hi] = __builtin_amdgcn_mfma_f32_16x16x32_bf16(pa1, v1, o[hi], 0, 0, 0);
    }
    __syncthreads();
  }
  // reduce l across the 16 lanes of each quad-row group
#pragma unroll
  for (int d = 1; d < 16; d <<= 1)
#pragma unroll
    for (int r = 0; r < 4; ++r) lr[r] += __shfl_xor(lr[r], d, 64);
  // linear combine: atomicAdd un-normalized partials
  float* ob = out + ((size_t)b * T_ + t0 + quad * 4) * H_ + l15;
#pragma unroll
  for (int r = 0; r < 4; ++r)
#pragma unroll
    for (int hi = 0; hi < 4; ++hi)
      atomicAdd(ob + (size_t)r * H_ + 16 * hi, o[hi][r]);
  if (l15 == 0) {
#pragma unroll
    for (int r = 0; r < 4; ++r)
      atomicAdd(Lws + (size_t)b * T_ + t0 + quad * 4 + r, lr[r]);
  }
}

// ---------------------------------------------------------------------------
// normalize: out[row][:] /= Lws[row]. grid 1024, block 256 (16 rows/block).
// ---------------------------------------------------------------------------
__global__ __launch_bounds__(256)
void normalize(float4* __restrict__ out4, const float* __restrict__ Lws) {
  const int row = blockIdx.x * 16 + (threadIdx.x >> 4);
  const int c4  = threadIdx.x & 15;
  const float inv = 1.0f / Lws[row];
  float4 v = out4[(size_t)row * 16 + c4];
  v.x *= inv; v.y *= inv; v.z *= inv; v.w *= inv;
  out4[(size_t)row * 16 + c4] = v;
}

extern "C" void kernel_launch(void* const* d_in, const int* in_sizes, int n_in,
                              void* d_out, int out_size, void* d_ws, size_t ws_size,
                              hipStream_t stream) {
  const float* x  = (const float*)d_in[0];
  const float* Wk = (const float*)d_in[1];
  const float* Wq = (const float*)d_in[2];
  const float* Wv = (const float*)d_in[3];
  u16*   ws  = (u16*)d_ws;
  u16*   Wct = ws + (size_t)3 * BTH;
  float* Lws = (float*)(ws + LWS_OFF);
  float* out = (float*)d_out;
  zero_out<<<dim3(1040), 256, 0, stream>>>((float4*)out, (float4*)Lws);
  wpack<<<dim3(3, 16), 256, 0, stream>>>(Wk, Wq, Wv, Wct);
  qkv_gemm<<<dim3(512), 512, 0, stream>>>(x, Wct, ws);
  flash<<<dim3(64, B_, 4), 128, 0, stream>>>(ws, out, Lws);
  normalize<<<dim3(1024), 256, 0, stream>>>((float4*)out, Lws);
}